// Round 1
// baseline (176.375 us; speedup 1.0000x reference)
//
#include <hip/hip_runtime.h>

// Problem constants
#define B_  32
#define M_  64
#define K_  36
#define DS_ 512
#define DX_ 128
#define DQ_ 512
#define H_  256

#define TMA 16   // rows per GEMM tile in kern1

// ---------------------------------------------------------------------------
// kern1 (grid 360 x 512 threads): all GEMMs, full-K per block (no atomics).
//   blocks [0,256):   tile=bid>>1, mat=bid&1 (0: pre_s=s2@w_s, 1: h1=s2@h_w1)
//                     K=512 split kh in {0,1} x 256, combined via LDS.
//   blocks [256,328): px[bk,h] = x0[bk]@w_x + score_b1   (K=128 split 2x64)
//   blocks [328,360): qpre[b,h] = q[b]@w_q               (K=512 split 2x256)
// s2/x0/q accessed with block-uniform addresses -> scalar (s_load) path.
// ---------------------------------------------------------------------------
__global__ __launch_bounds__(512) void kern1(
    const float* __restrict__ s2,        // (2048,512)
    const float* __restrict__ x0,        // (1152,128)
    const float* __restrict__ q,         // (32,512)
    const float* __restrict__ score_w1,  // (1152,256)
    const float* __restrict__ score_b1,  // (256)
    const float* __restrict__ h_w1,      // (512,256)
    float* __restrict__ pre_s,           // (2048,256)
    float* __restrict__ h1,              // (2048,256)
    float* __restrict__ px,              // (1152,256)
    float* __restrict__ qpre)            // (32,256)
{
    __shared__ float comb[TMA * H_];     // 16 KB
    const int t   = threadIdx.x;
    const int kh  = t >> 8;              // 0/1 : K-half
    const int h   = t & 255;
    const int bid = blockIdx.x;

    if (bid < 256) {                     // ---- s2 GEMMs ----
        const int tile = bid >> 1, mat = bid & 1;
        const float* w  = (mat ? h_w1 : score_w1) + (size_t)(kh * 256) * H_ + h;
        const float* sp = s2 + (size_t)tile * TMA * DS_ + kh * 256;  // uniform

        float acc[TMA];
        #pragma unroll
        for (int i = 0; i < TMA; ++i) acc[i] = 0.f;

        for (int d = 0; d < 256; d += 4) {
            const float w0  = w[(size_t)(d + 0) * H_];
            const float w1  = w[(size_t)(d + 1) * H_];
            const float w2v = w[(size_t)(d + 2) * H_];
            const float w3  = w[(size_t)(d + 3) * H_];
            #pragma unroll
            for (int i = 0; i < TMA; ++i) {
                const float4 s4 = *(const float4*)(sp + (size_t)i * DS_ + d);
                acc[i] = fmaf(s4.x, w0,  acc[i]);
                acc[i] = fmaf(s4.y, w1,  acc[i]);
                acc[i] = fmaf(s4.z, w2v, acc[i]);
                acc[i] = fmaf(s4.w, w3,  acc[i]);
            }
        }
        if (kh) {
            #pragma unroll
            for (int i = 0; i < TMA; ++i) comb[i * H_ + h] = acc[i];
        }
        __syncthreads();
        if (!kh) {
            float* dst = (mat ? h1 : pre_s) + (size_t)tile * TMA * H_ + h;
            #pragma unroll
            for (int i = 0; i < TMA; ++i)
                dst[(size_t)i * H_] = acc[i] + comb[i * H_ + h];
        }
    } else if (bid < 328) {              // ---- px blocks ----
        const int tile = bid - 256;
        const float* w  = score_w1 + (size_t)(DS_ + kh * 64) * H_ + h;
        const float* sp = x0 + (size_t)tile * TMA * DX_ + kh * 64;   // uniform

        float acc[TMA];
        #pragma unroll
        for (int i = 0; i < TMA; ++i) acc[i] = 0.f;

        for (int d = 0; d < 64; d += 4) {
            const float w0  = w[(size_t)(d + 0) * H_];
            const float w1  = w[(size_t)(d + 1) * H_];
            const float w2v = w[(size_t)(d + 2) * H_];
            const float w3  = w[(size_t)(d + 3) * H_];
            #pragma unroll
            for (int i = 0; i < TMA; ++i) {
                const float4 s4 = *(const float4*)(sp + (size_t)i * DX_ + d);
                acc[i] = fmaf(s4.x, w0,  acc[i]);
                acc[i] = fmaf(s4.y, w1,  acc[i]);
                acc[i] = fmaf(s4.z, w2v, acc[i]);
                acc[i] = fmaf(s4.w, w3,  acc[i]);
            }
        }
        if (kh) {
            #pragma unroll
            for (int i = 0; i < TMA; ++i) comb[i * H_ + h] = acc[i];
        }
        __syncthreads();
        if (!kh) {
            const float b1 = score_b1[h];
            float* dst = px + (size_t)tile * TMA * H_ + h;
            #pragma unroll
            for (int i = 0; i < TMA; ++i)
                dst[(size_t)i * H_] = acc[i] + comb[i * H_ + h] + b1;
        }
    } else {                             // ---- qpre blocks ----
        const int b = bid - 328;
        const float* qp = q + (size_t)b * DQ_ + kh * 256;            // uniform
        const float* wq = score_w1 + (size_t)(DS_ + DX_ + kh * 256) * H_ + h;
        float a0 = 0.f, a1 = 0.f, a2 = 0.f, a3 = 0.f;
        for (int d = 0; d < 256; d += 4) {
            const float4 q4 = *(const float4*)(qp + d);
            a0 = fmaf(q4.x, wq[(size_t)(d + 0) * H_], a0);
            a1 = fmaf(q4.y, wq[(size_t)(d + 1) * H_], a1);
            a2 = fmaf(q4.z, wq[(size_t)(d + 2) * H_], a2);
            a3 = fmaf(q4.w, wq[(size_t)(d + 3) * H_], a3);
        }
        const float s = (a0 + a1) + (a2 + a3);
        if (kh) comb[h] = s;
        __syncthreads();
        if (!kh) qpre[(size_t)b * H_ + h] = s + comb[h];
    }
}

// ---------------------------------------------------------------------------
// kern2 (grid 256 x 256): hs = relu(h1 + h_b1) @ h_w2  (2048x256 @ 256x128)
//   8 rows per block; relu'd A tile staged once in LDS (broadcast reads).
// ---------------------------------------------------------------------------
__global__ __launch_bounds__(256) void kern2(
    const float* __restrict__ h1,        // (2048,256)
    const float* __restrict__ h_b1,      // (256)
    const float* __restrict__ h_w2,      // (256,128)
    float* __restrict__ hs)              // (2048,128)
{
    __shared__ float A[8 * H_];          // 8 KB
    const int t  = threadIdx.x;
    const int r0 = blockIdx.x * 8;

    #pragma unroll
    for (int i = 0; i < 2; ++i) {
        const int flat = t * 4 + i * 1024;
        const float4 v = *(const float4*)(h1 + (size_t)r0 * H_ + flat);
        const float4 bb = *(const float4*)(h_b1 + (flat & 255));
        float4 a;
        a.x = fmaxf(v.x + bb.x, 0.f);
        a.y = fmaxf(v.y + bb.y, 0.f);
        a.z = fmaxf(v.z + bb.z, 0.f);
        a.w = fmaxf(v.w + bb.w, 0.f);
        *(float4*)&A[flat] = a;
    }
    __syncthreads();

    const int f  = t & 127;
    const int rh = t >> 7;               // rows rh*4 .. rh*4+3
    const float* wp = h_w2 + f;
    const float* Ap = &A[rh * 4 * H_];

    float a0 = 0.f, a1 = 0.f, a2 = 0.f, a3 = 0.f;
    for (int d = 0; d < 256; d += 4) {
        const float w0  = wp[(size_t)(d + 0) * DX_];
        const float w1  = wp[(size_t)(d + 1) * DX_];
        const float w2v = wp[(size_t)(d + 2) * DX_];
        const float w3  = wp[(size_t)(d + 3) * DX_];
        const float4 x0v = *(const float4*)&Ap[0 * H_ + d];
        const float4 x1v = *(const float4*)&Ap[1 * H_ + d];
        const float4 x2v = *(const float4*)&Ap[2 * H_ + d];
        const float4 x3v = *(const float4*)&Ap[3 * H_ + d];
        a0 = fmaf(x0v.x, w0, a0); a0 = fmaf(x0v.y, w1, a0);
        a0 = fmaf(x0v.z, w2v, a0); a0 = fmaf(x0v.w, w3, a0);
        a1 = fmaf(x1v.x, w0, a1); a1 = fmaf(x1v.y, w1, a1);
        a1 = fmaf(x1v.z, w2v, a1); a1 = fmaf(x1v.w, w3, a1);
        a2 = fmaf(x2v.x, w0, a2); a2 = fmaf(x2v.y, w1, a2);
        a2 = fmaf(x2v.z, w2v, a2); a2 = fmaf(x2v.w, w3, a2);
        a3 = fmaf(x3v.x, w0, a3); a3 = fmaf(x3v.y, w1, a3);
        a3 = fmaf(x3v.z, w2v, a3); a3 = fmaf(x3v.w, w3, a3);
    }
    float* dst = hs + (size_t)(r0 + rh * 4) * DX_ + f;
    dst[0 * DX_] = a0;
    dst[1 * DX_] = a1;
    dst[2 * DX_] = a2;
    dst[3 * DX_] = a3;
}

// ---------------------------------------------------------------------------
// kern3 (grid 288 = 32 b x 9 kgroups, 256 threads): logits+softmax+agg.
//   KG=4 k's per block. pre_s[b] staged in LDS with XOR swizzle
//   (h ^= (m&7)<<2) -> lane-per-m serial-h loop is bank-conflict-free.
//   Wave kk handles k0+kk; softmax = one 64-lane shuffle reduce.
//   agg uses precomputed hs; h_b2 added at the end (sum att = 1).
// ---------------------------------------------------------------------------
__global__ __launch_bounds__(256) void kern3(
    const float* __restrict__ pre_s,     // (2048,256)
    const float* __restrict__ px,        // (1152,256)
    const float* __restrict__ qpre,      // (32,256)
    const float* __restrict__ score_w2,  // (256,1)
    const float* __restrict__ hs,        // (2048,128)
    const float* __restrict__ h_b2,      // (128)
    const float* __restrict__ x0,        // (1152,128)
    float* __restrict__ out)             // (1152,256)
{
    __shared__ float psf[M_ * H_];       // 64 KB, swizzled
    __shared__ float cw4[4][H_];         // 4 KB
    __shared__ float att4[M_ * 4];       // 1 KB, [m][kk]
    __shared__ float pr[4][DX_];         // 2 KB

    const int t   = threadIdx.x;
    const int b   = blockIdx.x / 9;
    const int k0  = (blockIdx.x % 9) * 4;
    const int bk0 = b * K_ + k0;

    // ---- stage pre_s[b] into LDS (swizzled), coalesced float4 loads ----
    const float* psrc = pre_s + (size_t)b * M_ * H_;
    #pragma unroll
    for (int i = 0; i < 16; ++i) {
        const int flat = t * 4 + i * 1024;
        const float4 v = *(const float4*)(psrc + flat);
        const int m = flat >> 8, hh = flat & 255;
        *(float4*)&psf[m * H_ + (hh ^ ((m & 7) << 2))] = v;
    }
    // ---- cw4[kk][h] = px[bk0+kk,h] + qpre[b,h] ----
    {
        const float qv = qpre[(size_t)b * H_ + t];
        #pragma unroll
        for (int kk = 0; kk < 4; ++kk)
            cw4[kk][t] = px[(size_t)(bk0 + kk) * H_ + t] + qv;
    }
    __syncthreads();

    // ---- logits + softmax: wave = kk, lane = m ----
    {
        const int kk = t >> 6, m = t & 63;
        const int sw = (m & 7) << 2;
        const float* prow = &psf[m * H_];
        const float* crow = &cw4[kk][0];
        float lg = 0.f;
        for (int d = 0; d < 256; d += 4) {
            const float4 p = *(const float4*)&prow[d ^ sw];
            const float4 c = *(const float4*)&crow[d];      // LDS broadcast
            const float4 v = *(const float4*)(score_w2 + d);// uniform -> s_load
            lg += fmaxf(p.x + c.x, 0.f) * v.x + fmaxf(p.y + c.y, 0.f) * v.y
                + fmaxf(p.z + c.z, 0.f) * v.z + fmaxf(p.w + c.w, 0.f) * v.w;
        }
        float mx = lg;
        #pragma unroll
        for (int off = 32; off > 0; off >>= 1)
            mx = fmaxf(mx, __shfl_xor(mx, off, 64));
        const float e = expf(lg - mx);
        float sm = e;
        #pragma unroll
        for (int off = 32; off > 0; off >>= 1)
            sm += __shfl_xor(sm, off, 64);
        att4[m * 4 + kk] = e / sm;
    }
    __syncthreads();

    // ---- agg: out[bk0+kk, 128+f] = sum_m att[m,kk]*hs[b,m,f] + h_b2[f] ----
    const int f = t & 127, half = t >> 7;
    {
        const float* hsp = hs + ((size_t)b * M_ + half * 32) * DX_ + f;
        float r0 = 0.f, r1 = 0.f, r2 = 0.f, r3 = 0.f;
        for (int m = 0; m < 32; ++m) {
            const float hv = hsp[(size_t)m * DX_];
            const float4 a = *(const float4*)&att4[(half * 32 + m) * 4];
            r0 = fmaf(a.x, hv, r0);
            r1 = fmaf(a.y, hv, r1);
            r2 = fmaf(a.z, hv, r2);
            r3 = fmaf(a.w, hv, r3);
        }
        if (half) {
            pr[0][f] = r0; pr[1][f] = r1; pr[2][f] = r2; pr[3][f] = r3;
        }
        __syncthreads();
        if (!half) {
            const float b2 = h_b2[f];
            out[(size_t)(bk0 + 0) * (2 * DX_) + DX_ + f] = r0 + pr[0][f] + b2;
            out[(size_t)(bk0 + 1) * (2 * DX_) + DX_ + f] = r1 + pr[1][f] + b2;
            out[(size_t)(bk0 + 2) * (2 * DX_) + DX_ + f] = r2 + pr[2][f] + b2;
            out[(size_t)(bk0 + 3) * (2 * DX_) + DX_ + f] = r3 + pr[3][f] + b2;
        }
    }
    // ---- passthrough out[:,0:128] = x0 ----
    #pragma unroll
    for (int j = 0; j < 2; ++j) {
        const int kk = half * 2 + j;
        out[(size_t)(bk0 + kk) * (2 * DX_) + f] = x0[(size_t)(bk0 + kk) * DX_ + f];
    }
}

extern "C" void kernel_launch(void* const* d_in, const int* in_sizes, int n_in,
                              void* d_out, int out_size, void* d_ws, size_t ws_size,
                              hipStream_t stream) {
    (void)in_sizes; (void)n_in; (void)out_size; (void)ws_size;
    const float* s2       = (const float*)d_in[0];
    const float* x0       = (const float*)d_in[1];
    const float* q        = (const float*)d_in[2];
    const float* score_w1 = (const float*)d_in[3];
    const float* score_b1 = (const float*)d_in[4];
    const float* score_w2 = (const float*)d_in[5];
    // d_in[6] = score_b2 (cancels in softmax)
    const float* h_w1     = (const float*)d_in[7];
    const float* h_b1     = (const float*)d_in[8];
    const float* h_w2     = (const float*)d_in[9];
    const float* h_b2     = (const float*)d_in[10];
    float* out = (float*)d_out;

    float* ws    = (float*)d_ws;
    float* pre_s = ws;                                   // 2048*256
    float* h1    = pre_s + (size_t)B_ * M_ * H_;         // 2048*256
    float* px    = h1    + (size_t)B_ * M_ * H_;         // 1152*256
    float* qpre  = px    + (size_t)B_ * K_ * H_;         // 32*256
    float* hs    = qpre  + (size_t)B_ * H_;              // 2048*128

    kern1<<<360, 512, 0, stream>>>(s2, x0, q, score_w1, score_b1, h_w1,
                                   pre_s, h1, px, qpre);
    kern2<<<256, 256, 0, stream>>>(h1, h_b1, h_w2, hs);
    kern3<<<288, 256, 0, stream>>>(pre_s, px, qpre, score_w2, hs, h_b2, x0, out);
}